// Round 12
// baseline (717.043 us; speedup 1.0000x reference)
//
#include <hip/hip_runtime.h>
#include <hip/hip_bf16.h>

typedef _Float16 f16x8 __attribute__((ext_vector_type(8)));
typedef _Float16 f16x4 __attribute__((ext_vector_type(4)));
typedef float f32x4 __attribute__((ext_vector_type(4)));

#define H 128
#define FEAT 7
#define RB 64      // rows per block
#define NT 512     // threads per block (8 waves)

__device__ __forceinline__ float conv3(float x, float w, float b) {
    x = fmaxf(fmaf(w, x, b), 0.f);
    x = fmaxf(fmaf(w, x, b), 0.f);
    x = fmaxf(fmaf(w, x, b), 0.f);
    return x;
}
__device__ __forceinline__ float sigm(float x) {
    return __builtin_amdgcn_rcpf(1.f + __expf(-x));
}

// Pack fp32 row-major W[k][n] -> f16 MFMA fragment layout: P[((k>>3)*N + n)*8 + (k&7)]
// Pu is Wu padded to K=32 with zeros (k>=7) so the u-GEMM needs no lane masking.
__global__ __launch_bounds__(256) void pack_weights(
    const float* __restrict__ Wu, const float* __restrict__ Wr,
    const float* __restrict__ Wh, const float* __restrict__ Wz,
    _Float16* __restrict__ Pu, _Float16* __restrict__ Pr,
    _Float16* __restrict__ Ph, _Float16* __restrict__ Pz)
{
    int idx = blockIdx.x * 256 + threadIdx.x;
    if (idx < 384 * 384) {
        int k = idx / 384, n = idx % 384;
        Pr[((size_t)(k >> 3) * 384 + n) * 8 + (k & 7)] = (_Float16)Wr[idx];
    }
    if (idx < 384 * 128) {
        int k = idx / 128, n = idx % 128;
        Ph[((size_t)(k >> 3) * 128 + n) * 8 + (k & 7)] = (_Float16)Wh[idx];
    }
    if (idx < 512 * 512) {
        int k = idx / 512, n = idx % 512;
        Pz[((size_t)(k >> 3) * 512 + n) * 8 + (k & 7)] = (_Float16)Wz[idx];
    }
    if (idx < 128 * 32) {
        int n = idx & 127, kk = idx >> 7;   // kk = 0..31
        Pu[((size_t)(kk >> 3) * 128 + n) * 8 + (kk & 7)] =
            (kk < FEAT) ? (_Float16)Wu[kk * H + n] : (_Float16)0.f;
    }
}

// Fused level kernel: 64 rows / 512 threads (8 waves) — measured-best hybrid,
// depth-2 prefetch everywhere (depth-3 regressed in R11):
//  * LEAF: block-shared content staging (R9 body, measured 323 us).
//  * non-LEAF: per-wave staging, no extra barrier (R6 body, measured 349 us).
// Per-wave ratio 4 MFMA per weight-b128; depth-2 rotating prefetch (3 slots,
// static %3 indices) on weight (global/L2) and B-fragment (LDS) streams.
template<bool LEAF>
__global__ __launch_bounds__(NT, 2) void level_kernel(
    const float* __restrict__ contents,     // pre-offset, (n,7)
    const int* __restrict__ children,       // pre-offset, (n,2)
    const float* __restrict__ leafContents, // level-9 contents (LEAF only)
    const _Float16* __restrict__ embPrev,   // (!LEAF)
    _Float16* __restrict__ embOut,
    float* __restrict__ finalOut,           // non-null only at level 0
    const _Float16* __restrict__ Pu, const float* __restrict__ bu,
    const _Float16* __restrict__ Pr, const float* __restrict__ br,
    const _Float16* __restrict__ Ph, const float* __restrict__ bh,
    const _Float16* __restrict__ Pz, const float* __restrict__ bz,
    const float* __restrict__ convw, const float* __restrict__ convb)
{
    __shared__ __align__(16) _Float16 s_hhu[RB][392];  // [h_L | h_R | u]
    __shared__ __align__(16) _Float16 s_x[RB][392];    // r*hhu (staging alias early)
    __shared__ __align__(16) _Float16 s_hH[RB][136];   // conv3 output (own buffer)

    const int t = threadIdx.x;
    const int row0 = blockIdx.x * RB;
    const float cw = convw[0], cbv = convb[0];

    const int lane = t & 63;
    const int w = t >> 6;                  // 0..7
    const int q = lane >> 4;               // 0..3 (k-chunk)
    const int ln = lane & 15;

    // ---- Stage C weight pointer + depth-2 preload (issued FIRST so the cold
    // L2 latency hides under the staging + u-stage)
    const f16x8* PBc = (const f16x8*)Pr + (w * 48 + ln);
    f16x8 awc[3][3];
#pragma unroll
    for (int c = 0; c < 3; c++) awc[0][c] = PBc[(size_t)q * 384 + c * 16];
#pragma unroll
    for (int c = 0; c < 3; c++) awc[1][c] = PBc[(size_t)(4 + q) * 384 + c * 16];

    // ---- Stage A/B: content staging + u = conv3(c @ Wu + bu) via MFMA ----
    if (LEAF) {
        // Block-shared staging: wbuf = [192 rows][8] f16 in the (dead) s_x
        // region; k<7 data, k=7 zero; one b128 read = u-GEMM B-fragment.
        _Float16* wbuf = (_Float16*)&s_x[0][0];
        {
            int r = t >> 3, k = t & 7;
            wbuf[t] = (k < FEAT) ? (_Float16)contents[(size_t)(row0 + r) * FEAT + k]
                                 : (_Float16)0.f;
            // leaf children of rows [row0,row0+64) are contiguous rows
            // [base, base+128) of level-9 contents (ch = [2i,2i+1] construction)
            int base = children[row0 * 2];
            const float* lc = leafContents + (size_t)base * FEAT;
#pragma unroll
            for (int p = 0; p < 2; p++) {
                int e = p * 512 + t;                 // 0..1023 = 128 rows x 8
                int r2 = e >> 3, k2 = e & 7;
                wbuf[512 + e] = (k2 < FEAT) ? (_Float16)lc[(size_t)r2 * FEAT + k2]
                                            : (_Float16)0.f;
            }
        }
        __syncthreads();
        f16x8 puF = ((const f16x8*)Pu)[(size_t)q * 128 + w * 16 + ln];
        const int fb = w * 16 + q * 4;
        f32x4 buv = *(const f32x4*)&bu[fb];
        {
            f16x8 bA[4];
#pragma unroll
            for (int rt = 0; rt < 4; rt++)
                bA[rt] = *(const f16x8*)&wbuf[(rt * 16 + ln) * 8];
            f32x4 accA[4];
#pragma unroll
            for (int rt = 0; rt < 4; rt++)
                accA[rt] = __builtin_amdgcn_mfma_f32_16x16x32_f16(puF, bA[rt], (f32x4){0,0,0,0}, 0, 0, 0);
#pragma unroll
            for (int rt = 0; rt < 4; rt++) {
                f16x4 hp;
#pragma unroll
                for (int reg = 0; reg < 4; reg++)
                    hp[reg] = (_Float16)conv3(accA[rt][reg] + buv[reg], cw, cbv);
                *(f16x4*)&s_hhu[rt * 16 + ln][256 + fb] = hp;
            }
        }
#pragma unroll
        for (int h = 0; h < 2; h++) {
            f16x8 bB[4];
#pragma unroll
            for (int rt = 0; rt < 4; rt++)
                bB[rt] = *(const f16x8*)&wbuf[512 + ((h * 4 + rt) * 16 + ln) * 8];
            f32x4 accB[4];
#pragma unroll
            for (int rt = 0; rt < 4; rt++)
                accB[rt] = __builtin_amdgcn_mfma_f32_16x16x32_f16(puF, bB[rt], (f32x4){0,0,0,0}, 0, 0, 0);
#pragma unroll
            for (int rt = 0; rt < 4; rt++) {
                int rr = (h * 4 + rt) * 16 + ln;  // child row 0..127
                f16x4 hp;
#pragma unroll
                for (int reg = 0; reg < 4; reg++)
                    hp[reg] = (_Float16)conv3(accB[rt][reg] + buv[reg], cw, cbv);
                *(f16x4*)&s_hhu[rr >> 1][(rr & 1) * 128 + fb] = hp;
            }
        }
    } else {
        // Per-wave staging (no extra barrier): wave-private wbuf in s_x region.
        _Float16* wbuf = (_Float16*)&s_x[0][0] + (size_t)w * 512; // 64 rows x 8
        {
            wbuf[lane * 8 + 7] = (_Float16)0.f;
#pragma unroll
            for (int it = 0; it < 7; it++) {
                int i = it * 64 + lane;                  // i < 448 = 64*7
                float v = contents[(size_t)row0 * FEAT + i];
                int r = i / 7, k = i - r * 7;
                wbuf[r * 8 + k] = (_Float16)v;
            }
            int rp = t >> 4, chunk = t & 15;   // rp 0..31
#pragma unroll
            for (int p = 0; p < 4; p++) {
                int cr = p * 32 + rp;          // 0..127
                int child = children[row0 * 2 + cr];
                uint4 v = *(const uint4*)(embPrev + (size_t)child * H + chunk * 8);
                *(uint4*)&s_hhu[cr >> 1][(cr & 1) * 128 + chunk * 8] = v;
            }
        }
        f16x8 puF = ((const f16x8*)Pu)[(size_t)q * 128 + w * 16 + ln];
        const int fb = w * 16 + q * 4;
        f32x4 buv = *(const f32x4*)&bu[fb];
        f16x8 bA[4];
#pragma unroll
        for (int rt = 0; rt < 4; rt++)
            bA[rt] = *(const f16x8*)&wbuf[(rt * 16 + ln) * 8];
        f32x4 accA[4];
#pragma unroll
        for (int rt = 0; rt < 4; rt++)
            accA[rt] = __builtin_amdgcn_mfma_f32_16x16x32_f16(puF, bA[rt], (f32x4){0,0,0,0}, 0, 0, 0);
#pragma unroll
        for (int rt = 0; rt < 4; rt++) {
            f16x4 hp;
#pragma unroll
            for (int reg = 0; reg < 4; reg++)
                hp[reg] = (_Float16)conv3(accA[rt][reg] + buv[reg], cw, cbv);
            *(f16x4*)&s_hhu[rt * 16 + ln][256 + fb] = hp;
        }
    }
    __syncthreads();

    const f16x8* PBd = (const f16x8*)Ph + (w * 16 + ln);
    f16x8 awd[3];

    // ---- Stage C: r = sigmoid(hhu @ Wr + br); x = r * hhu
    // wave w owns 48 output features (3 n-tiles), all 64 rows (4 m-tiles)
    {
        f32x4 acc[3][4];
#pragma unroll
        for (int c = 0; c < 3; c++)
#pragma unroll
            for (int rt = 0; rt < 4; rt++) acc[c][rt] = (f32x4){0,0,0,0};
        f16x8 bb[3][4];
#pragma unroll
        for (int rt = 0; rt < 4; rt++) bb[0][rt] = *(const f16x8*)&s_hhu[rt * 16 + ln][q * 8];
#pragma unroll
        for (int rt = 0; rt < 4; rt++) bb[1][rt] = *(const f16x8*)&s_hhu[rt * 16 + ln][32 + q * 8];
#pragma unroll
        for (int kk = 0; kk < 12; kk++) {
            // depth-2 prefetch: weights (global/L2) then B-fragments (LDS)
            if (kk + 2 < 12) {
                int kb = (kk + 2) * 4 + q;
#pragma unroll
                for (int c = 0; c < 3; c++) awc[(kk + 2) % 3][c] = PBc[(size_t)kb * 384 + c * 16];
#pragma unroll
                for (int rt = 0; rt < 4; rt++)
                    bb[(kk + 2) % 3][rt] = *(const f16x8*)&s_hhu[rt * 16 + ln][(kk + 2) * 32 + q * 8];
            }
#pragma unroll
            for (int c = 0; c < 3; c++)
#pragma unroll
                for (int rt = 0; rt < 4; rt++)
                    acc[c][rt] = __builtin_amdgcn_mfma_f32_16x16x32_f16(awc[kk % 3][c], bb[kk % 3][rt], acc[c][rt], 0, 0, 0);
        }
        // preload stage D weights; latency hides under the epilogue + barrier
        awd[0] = PBd[(size_t)q * 128];
        awd[1] = PBd[(size_t)(4 + q) * 128];
        // epilogue: lane holds features fb..fb+3 of row rt*16+ln
#pragma unroll
        for (int c = 0; c < 3; c++) {
            int fb = w * 48 + c * 16 + q * 4;
            f32x4 bv = *(const f32x4*)&br[fb];
#pragma unroll
            for (int rt = 0; rt < 4; rt++) {
                int row = rt * 16 + ln;
                f16x4 hh = *(const f16x4*)&s_hhu[row][fb];
                f16x4 xv;
#pragma unroll
                for (int reg = 0; reg < 4; reg++) {
                    float rv = sigm(acc[c][rt][reg] + bv[reg]);
                    xv[reg] = (_Float16)(rv * (float)hh[reg]);
                }
                *(f16x4*)&s_x[row][fb] = xv;
            }
        }
    }
    __syncthreads();

    const f16x8* PBe = (const f16x8*)Pz + (w * 16 + ln);
    f16x8 awe[3][4];

    // ---- Stage D: h_H = conv3(x @ Wh + bh); wave w owns 16 features, 64 rows
    {
        f32x4 acc[4];
#pragma unroll
        for (int rt = 0; rt < 4; rt++) acc[rt] = (f32x4){0,0,0,0};
        f16x8 bb[3][4];
#pragma unroll
        for (int rt = 0; rt < 4; rt++) bb[0][rt] = *(const f16x8*)&s_x[rt * 16 + ln][q * 8];
#pragma unroll
        for (int rt = 0; rt < 4; rt++) bb[1][rt] = *(const f16x8*)&s_x[rt * 16 + ln][32 + q * 8];
#pragma unroll
        for (int kk = 0; kk < 12; kk++) {
            if (kk + 2 < 12) {
                int kb = (kk + 2) * 4 + q;
                awd[(kk + 2) % 3] = PBd[(size_t)kb * 128];
#pragma unroll
                for (int rt = 0; rt < 4; rt++)
                    bb[(kk + 2) % 3][rt] = *(const f16x8*)&s_x[rt * 16 + ln][(kk + 2) * 32 + q * 8];
            }
#pragma unroll
            for (int rt = 0; rt < 4; rt++)
                acc[rt] = __builtin_amdgcn_mfma_f32_16x16x32_f16(awd[kk % 3], bb[kk % 3][rt], acc[rt], 0, 0, 0);
        }
        // preload stage E weights (depth-2); latency hides under epilogue+barrier
#pragma unroll
        for (int g = 0; g < 4; g++) awe[0][g] = PBe[(size_t)q * 512 + g * 128];
#pragma unroll
        for (int g = 0; g < 4; g++) awe[1][g] = PBe[(size_t)(4 + q) * 512 + g * 128];
        // epilogue: conv3 then write to the dedicated s_hH buffer
        int fb = w * 16 + q * 4;
        f32x4 bhv = *(const f32x4*)&bh[fb];
#pragma unroll
        for (int rt = 0; rt < 4; rt++) {
            f16x4 hp;
#pragma unroll
            for (int reg = 0; reg < 4; reg++)
                hp[reg] = (_Float16)conv3(acc[rt][reg] + bhv[reg], cw, cbv);
            *(f16x4*)&s_hH[rt * 16 + ln][fb] = hp;
        }
    }
    __syncthreads();

    // ---- Stage E: z = [h_H | hhu] @ Wz + bz; softmax gate; write out
    // wave w owns 16 z-cols (x 4 gate groups at stride 128), all 64 rows
    {
        const int nb = w * 16;
        f32x4 acc[4][4];                   // [gate group][m-tile]
#pragma unroll
        for (int g = 0; g < 4; g++)
#pragma unroll
            for (int rt = 0; rt < 4; rt++) acc[g][rt] = (f32x4){0,0,0,0};
        f16x8 bb[3][4];
#pragma unroll
        for (int rt = 0; rt < 4; rt++) bb[0][rt] = *(const f16x8*)&s_hH[rt * 16 + ln][q * 8];
#pragma unroll
        for (int rt = 0; rt < 4; rt++) bb[1][rt] = *(const f16x8*)&s_hH[rt * 16 + ln][32 + q * 8];
#pragma unroll
        for (int kk = 0; kk < 16; kk++) {
            if (kk + 2 < 16) {
                int kb = (kk + 2) * 4 + q;
#pragma unroll
                for (int g = 0; g < 4; g++) awe[(kk + 2) % 3][g] = PBe[(size_t)kb * 512 + g * 128];
                if (kk + 2 < 4) {
#pragma unroll
                    for (int rt = 0; rt < 4; rt++)
                        bb[(kk + 2) % 3][rt] = *(const f16x8*)&s_hH[rt * 16 + ln][(kk + 2) * 32 + q * 8];
                } else {
                    int k0 = (kk + 2) * 32 - 128;
#pragma unroll
                    for (int rt = 0; rt < 4; rt++)
                        bb[(kk + 2) % 3][rt] = *(const f16x8*)&s_hhu[rt * 16 + ln][k0 + q * 8];
                }
            }
#pragma unroll
            for (int g = 0; g < 4; g++)
#pragma unroll
                for (int rt = 0; rt < 4; rt++)
                    acc[g][rt] = __builtin_amdgcn_mfma_f32_16x16x32_f16(awe[kk % 3][g], bb[kk % 3][rt], acc[g][rt], 0, 0, 0);
        }
        // epilogue: lane holds z-cols colb..colb+3 (x 4 gate groups) of rows rt*16+ln
        int colb = nb + q * 4;
        f32x4 bz0 = *(const f32x4*)&bz[colb];
        f32x4 bz1 = *(const f32x4*)&bz[128 + colb];
        f32x4 bz2 = *(const f32x4*)&bz[256 + colb];
        f32x4 bz3 = *(const f32x4*)&bz[384 + colb];
#pragma unroll
        for (int rt = 0; rt < 4; rt++) {
            int row = rt * 16 + ln;
            f16x4 hH4 = *(const f16x4*)&s_hH[row][colb];
            f16x4 hL4 = *(const f16x4*)&s_hhu[row][colb];
            f16x4 hR4 = *(const f16x4*)&s_hhu[row][128 + colb];
            f16x4 u4  = *(const f16x4*)&s_hhu[row][256 + colb];
            size_t gidx = (size_t)(row0 + row) * H + colb;
            if (finalOut) {
                f32x4 ov;
#pragma unroll
                for (int reg = 0; reg < 4; reg++) {
                    float z0 = acc[0][rt][reg] + bz0[reg];
                    float z1 = acc[1][rt][reg] + bz1[reg];
                    float z2 = acc[2][rt][reg] + bz2[reg];
                    float z3 = acc[3][rt][reg] + bz3[reg];
                    float m = fmaxf(fmaxf(z0, z1), fmaxf(z2, z3));
                    float e0 = __expf(z0 - m), e1 = __expf(z1 - m), e2 = __expf(z2 - m), e3 = __expf(z3 - m);
                    float inv = __builtin_amdgcn_rcpf(e0 + e1 + e2 + e3);
                    ov[reg] = (e0 * (float)hH4[reg] + e1 * (float)hL4[reg] +
                               e2 * (float)hR4[reg] + e3 * (float)u4[reg]) * inv;
                }
                *(f32x4*)&finalOut[gidx] = ov;
            } else {
                f16x4 ev;
#pragma unroll
                for (int reg = 0; reg < 4; reg++) {
                    float z0 = acc[0][rt][reg] + bz0[reg];
                    float z1 = acc[1][rt][reg] + bz1[reg];
                    float z2 = acc[2][rt][reg] + bz2[reg];
                    float z3 = acc[3][rt][reg] + bz3[reg];
                    float m = fmaxf(fmaxf(z0, z1), fmaxf(z2, z3));
                    float e0 = __expf(z0 - m), e1 = __expf(z1 - m), e2 = __expf(z2 - m), e3 = __expf(z3 - m);
                    float inv = __builtin_amdgcn_rcpf(e0 + e1 + e2 + e3);
                    ev[reg] = (_Float16)((e0 * (float)hH4[reg] + e1 * (float)hL4[reg] +
                                          e2 * (float)hR4[reg] + e3 * (float)u4[reg]) * inv);
                }
                *(f16x4*)&embOut[gidx] = ev;
            }
        }
    }
}

extern "C" void kernel_launch(void* const* d_in, const int* in_sizes, int n_in,
                              void* d_out, int out_size, void* d_ws, size_t ws_size,
                              hipStream_t stream) {
    const float* contents = (const float*)d_in[0];
    const int*   children = (const int*)d_in[1];
    const float* Wu = (const float*)d_in[2];
    const float* bu = (const float*)d_in[3];
    const float* Wh = (const float*)d_in[4];
    const float* bh = (const float*)d_in[5];
    const float* Wz = (const float*)d_in[6];
    const float* bz = (const float*)d_in[7];
    const float* Wr = (const float*)d_in[8];
    const float* br = (const float*)d_in[9];
    const float* convw = (const float*)d_in[10];
    const float* convb = (const float*)d_in[11];
    float* out = (float*)d_out;

    // Workspace: [packed weights ~1MB][bufA 64MB][bufB 64MB]
    _Float16* Pr = (_Float16*)d_ws;
    _Float16* Ph = Pr + 384 * 384;
    _Float16* Pz = Ph + 384 * 128;
    _Float16* Pu = Pz + 512 * 512;
    _Float16* bufA = (_Float16*)((char*)d_ws + (1 << 20));
    _Float16* bufB = bufA + (size_t)262144 * H;

    auto OFFS = [](int j) -> long long { return 1024LL * ((1LL << j) - 1); };

    pack_weights<<<(512 * 512 + 255) / 256, 256, 0, stream>>>(Wu, Wr, Wh, Wz, Pu, Pr, Ph, Pz);

    // Level 8 with fused leaf (level 9) computation
    {
        int n = 1024 << 8;
        level_kernel<true><<<n / RB, NT, 0, stream>>>(
            contents + OFFS(8) * FEAT, children + OFFS(8) * 2,
            contents + OFFS(9) * FEAT, nullptr, bufA, nullptr,
            Pu, bu, Pr, br, Ph, bh, Pz, bz, convw, convb);
    }

    _Float16* prev = bufA;
    _Float16* cur  = bufB;
    for (int j = 7; j >= 0; j--) {
        int n = 1024 << j;
        level_kernel<false><<<n / RB, NT, 0, stream>>>(
            contents + OFFS(j) * FEAT, children + OFFS(j) * 2,
            nullptr, prev, cur, (j == 0 ? out : nullptr),
            Pu, bu, Pr, br, Ph, bh, Pz, bz, convw, convb);
        _Float16* tmp = prev; prev = cur; cur = tmp;
    }
}

// Round 13
// 676.572 us; speedup vs baseline: 1.0598x; 1.0598x over previous
//
#include <hip/hip_runtime.h>
#include <hip/hip_bf16.h>

typedef _Float16 f16x8 __attribute__((ext_vector_type(8)));
typedef _Float16 f16x4 __attribute__((ext_vector_type(4)));
typedef float f32x4 __attribute__((ext_vector_type(4)));

#define H 128
#define FEAT 7
#define RB 64      // rows per block
#define NT 512     // threads per block (8 waves)

__device__ __forceinline__ float conv3(float x, float w, float b) {
    x = fmaxf(fmaf(w, x, b), 0.f);
    x = fmaxf(fmaf(w, x, b), 0.f);
    x = fmaxf(fmaf(w, x, b), 0.f);
    return x;
}
__device__ __forceinline__ float sigm(float x) {
    return __builtin_amdgcn_rcpf(1.f + __expf(-x));
}

// Pack fp32 row-major W[k][n] -> f16 MFMA fragment layout: P[((k>>3)*N + n)*8 + (k&7)]
// Pu is Wu padded to K=32 with zeros (k>=7) so the u-GEMM needs no lane masking.
__global__ __launch_bounds__(256) void pack_weights(
    const float* __restrict__ Wu, const float* __restrict__ Wr,
    const float* __restrict__ Wh, const float* __restrict__ Wz,
    _Float16* __restrict__ Pu, _Float16* __restrict__ Pr,
    _Float16* __restrict__ Ph, _Float16* __restrict__ Pz)
{
    int idx = blockIdx.x * 256 + threadIdx.x;
    if (idx < 384 * 384) {
        int k = idx / 384, n = idx % 384;
        Pr[((size_t)(k >> 3) * 384 + n) * 8 + (k & 7)] = (_Float16)Wr[idx];
    }
    if (idx < 384 * 128) {
        int k = idx / 128, n = idx % 128;
        Ph[((size_t)(k >> 3) * 128 + n) * 8 + (k & 7)] = (_Float16)Wh[idx];
    }
    if (idx < 512 * 512) {
        int k = idx / 512, n = idx % 512;
        Pz[((size_t)(k >> 3) * 512 + n) * 8 + (k & 7)] = (_Float16)Wz[idx];
    }
    if (idx < 128 * 32) {
        int n = idx & 127, kk = idx >> 7;   // kk = 0..31
        Pu[((size_t)(kk >> 3) * 128 + n) * 8 + (kk & 7)] =
            (kk < FEAT) ? (_Float16)Wu[kk * H + n] : (_Float16)0.f;
    }
}

// Fused level kernel: 64 rows / 512 threads (8 waves). Weights as MFMA A-operand
// (rows as B). u-embeddings (c @ Wu) computed via MFMA with wave-private f16
// staging (replaces ~336 broadcast VMEM + ~770 scalar VALU per wave). Weight
// streams keep depth-2 rotating prefetch; B-fragment streams depth-2 in C/D/E.
// [R12 post-mortem: this exact source is the measured champion at 677.6 us;
//  R7 32x32 / R8 16-wave / R9 shared-staging / R10 coop / R11 depth-3 /
//  R12 hybrid all measured neutral-to-worse.]
template<bool LEAF>
__global__ __launch_bounds__(NT, 2) void level_kernel(
    const float* __restrict__ contents,     // pre-offset, (n,7)
    const int* __restrict__ children,       // pre-offset, (n,2)
    const float* __restrict__ leafContents, // level-9 contents (LEAF only)
    const _Float16* __restrict__ embPrev,   // (!LEAF)
    _Float16* __restrict__ embOut,
    float* __restrict__ finalOut,           // non-null only at level 0
    const _Float16* __restrict__ Pu, const float* __restrict__ bu,
    const _Float16* __restrict__ Pr, const float* __restrict__ br,
    const _Float16* __restrict__ Ph, const float* __restrict__ bh,
    const _Float16* __restrict__ Pz, const float* __restrict__ bz,
    const float* __restrict__ convw, const float* __restrict__ convb)
{
    __shared__ __align__(16) _Float16 s_hhu[RB][392];  // [h_L | h_R | u]
    __shared__ __align__(16) _Float16 s_x[RB][392];    // r*hhu (staging alias early)
    __shared__ __align__(16) _Float16 s_hH[RB][136];   // conv3 output (own buffer)

    const int t = threadIdx.x;
    const int row0 = blockIdx.x * RB;
    const float cw = convw[0], cbv = convb[0];

    const int lane = t & 63;
    const int w = t >> 6;                  // 0..7
    const int q = lane >> 4;               // 0..3
    const int ln = lane & 15;

    // ---- Stage C weight pointer + depth-2 preload (issued FIRST so the cold
    // L2 latency hides under the u-stage)
    const f16x8* PBc = (const f16x8*)Pr + (w * 48 + ln);
    f16x8 awc[3][3];
#pragma unroll
    for (int c = 0; c < 3; c++) awc[0][c] = PBc[(size_t)q * 384 + c * 16];
#pragma unroll
    for (int c = 0; c < 3; c++) awc[1][c] = PBc[(size_t)(4 + q) * 384 + c * 16];

    // ---- Stage A/B: u = conv3(c @ Wu + bu) via MFMA ----
    // Wave-private staging into the (currently dead) s_x region: rows laid out
    // as [r][8] f16 (k<7 data, k=7 zero) so a single b128 read = B-fragment.
    {
        _Float16* wbuf = (_Float16*)&s_x[0][0] + (size_t)w * 1536; // 192 rows x 8
#pragma unroll
        for (int it = 0; it < 3; it++) {
            int r = it * 64 + lane;                  // r < 192
            wbuf[r * 8 + 7] = (_Float16)0.f;
        }
#pragma unroll
        for (int it = 0; it < 7; it++) {
            int i = it * 64 + lane;                  // i < 448 = 64*7
            float v = contents[(size_t)row0 * FEAT + i];
            int r = i / 7, k = i - r * 7;
            wbuf[r * 8 + k] = (_Float16)v;
        }
        if (LEAF) {
            // leaf children of rows [row0,row0+64) are contiguous rows
            // [base, base+128) of level-9 contents (ch = [2i,2i+1] construction)
            int base = children[row0 * 2];
            const float* lc = leafContents + (size_t)base * FEAT;
#pragma unroll
            for (int it = 0; it < 14; it++) {
                int i = it * 64 + lane;              // i < 896 = 128*7
                float v = lc[i];
                int r = i / 7, k = i - r * 7;
                wbuf[512 + r * 8 + k] = (_Float16)v; // cfB at row offset 64
            }
        }
        f16x8 puF = ((const f16x8*)Pu)[(size_t)q * 128 + w * 16 + ln];
        const int fb = w * 16 + q * 4;
        f32x4 buv = *(const f32x4*)&bu[fb];
        // this level's 64 rows -> u columns [w*16, w*16+16)
        {
            f16x8 bA[4];
#pragma unroll
            for (int rt = 0; rt < 4; rt++)
                bA[rt] = *(const f16x8*)&wbuf[(rt * 16 + ln) * 8];
            f32x4 accA[4];
#pragma unroll
            for (int rt = 0; rt < 4; rt++)
                accA[rt] = __builtin_amdgcn_mfma_f32_16x16x32_f16(puF, bA[rt], (f32x4){0,0,0,0}, 0, 0, 0);
#pragma unroll
            for (int rt = 0; rt < 4; rt++) {
                f16x4 hp;
#pragma unroll
                for (int reg = 0; reg < 4; reg++)
                    hp[reg] = (_Float16)conv3(accA[rt][reg] + buv[reg], cw, cbv);
                *(f16x4*)&s_hhu[rt * 16 + ln][256 + fb] = hp;
            }
        }
        if (LEAF) {
#pragma unroll
            for (int h = 0; h < 2; h++) {
                f16x8 bB[4];
#pragma unroll
                for (int rt = 0; rt < 4; rt++)
                    bB[rt] = *(const f16x8*)&wbuf[512 + ((h * 4 + rt) * 16 + ln) * 8];
                f32x4 accB[4];
#pragma unroll
                for (int rt = 0; rt < 4; rt++)
                    accB[rt] = __builtin_amdgcn_mfma_f32_16x16x32_f16(puF, bB[rt], (f32x4){0,0,0,0}, 0, 0, 0);
#pragma unroll
                for (int rt = 0; rt < 4; rt++) {
                    int rr = (h * 4 + rt) * 16 + ln;  // child row 0..127
                    f16x4 hp;
#pragma unroll
                    for (int reg = 0; reg < 4; reg++)
                        hp[reg] = (_Float16)conv3(accB[rt][reg] + buv[reg], cw, cbv);
                    *(f16x4*)&s_hhu[rr >> 1][(rr & 1) * 128 + fb] = hp;
                }
            }
        } else {
            int rp = t >> 4, chunk = t & 15;   // rp 0..31
#pragma unroll
            for (int p = 0; p < 4; p++) {
                int cr = p * 32 + rp;          // 0..127
                int child = children[row0 * 2 + cr];
                uint4 v = *(const uint4*)(embPrev + (size_t)child * H + chunk * 8);
                *(uint4*)&s_hhu[cr >> 1][(cr & 1) * 128 + chunk * 8] = v;
            }
        }
    }
    __syncthreads();

    const f16x8* PBd = (const f16x8*)Ph + (w * 16 + ln);
    f16x8 awd[3];

    // ---- Stage C: r = sigmoid(hhu @ Wr + br); x = r * hhu
    // wave w owns 48 output features (3 n-tiles), all 64 rows (4 m-tiles)
    {
        f32x4 acc[3][4];
#pragma unroll
        for (int c = 0; c < 3; c++)
#pragma unroll
            for (int rt = 0; rt < 4; rt++) acc[c][rt] = (f32x4){0,0,0,0};
        f16x8 bb[3][4];
#pragma unroll
        for (int rt = 0; rt < 4; rt++) bb[0][rt] = *(const f16x8*)&s_hhu[rt * 16 + ln][q * 8];
#pragma unroll
        for (int rt = 0; rt < 4; rt++) bb[1][rt] = *(const f16x8*)&s_hhu[rt * 16 + ln][32 + q * 8];
#pragma unroll
        for (int kk = 0; kk < 12; kk++) {
            // depth-2 prefetch: weights (global/L2) then B-fragments (LDS)
            if (kk + 2 < 12) {
                int kb = (kk + 2) * 4 + q;
#pragma unroll
                for (int c = 0; c < 3; c++) awc[(kk + 2) % 3][c] = PBc[(size_t)kb * 384 + c * 16];
#pragma unroll
                for (int rt = 0; rt < 4; rt++)
                    bb[(kk + 2) % 3][rt] = *(const f16x8*)&s_hhu[rt * 16 + ln][(kk + 2) * 32 + q * 8];
            }
#pragma unroll
            for (int c = 0; c < 3; c++)
#pragma unroll
                for (int rt = 0; rt < 4; rt++)
                    acc[c][rt] = __builtin_amdgcn_mfma_f32_16x16x32_f16(awc[kk % 3][c], bb[kk % 3][rt], acc[c][rt], 0, 0, 0);
        }
        // preload stage D weights; latency hides under the epilogue + barrier
        awd[0] = PBd[(size_t)q * 128];
        awd[1] = PBd[(size_t)(4 + q) * 128];
        // epilogue: lane holds features fb..fb+3 of row rt*16+ln
#pragma unroll
        for (int c = 0; c < 3; c++) {
            int fb = w * 48 + c * 16 + q * 4;
            f32x4 bv = *(const f32x4*)&br[fb];
#pragma unroll
            for (int rt = 0; rt < 4; rt++) {
                int row = rt * 16 + ln;
                f16x4 hh = *(const f16x4*)&s_hhu[row][fb];
                f16x4 xv;
#pragma unroll
                for (int reg = 0; reg < 4; reg++) {
                    float rv = sigm(acc[c][rt][reg] + bv[reg]);
                    xv[reg] = (_Float16)(rv * (float)hh[reg]);
                }
                *(f16x4*)&s_x[row][fb] = xv;
            }
        }
    }
    __syncthreads();

    const f16x8* PBe = (const f16x8*)Pz + (w * 16 + ln);
    f16x8 awe[3][4];

    // ---- Stage D: h_H = conv3(x @ Wh + bh); wave w owns 16 features, 64 rows
    {
        f32x4 acc[4];
#pragma unroll
        for (int rt = 0; rt < 4; rt++) acc[rt] = (f32x4){0,0,0,0};
        f16x8 bb[3][4];
#pragma unroll
        for (int rt = 0; rt < 4; rt++) bb[0][rt] = *(const f16x8*)&s_x[rt * 16 + ln][q * 8];
#pragma unroll
        for (int rt = 0; rt < 4; rt++) bb[1][rt] = *(const f16x8*)&s_x[rt * 16 + ln][32 + q * 8];
#pragma unroll
        for (int kk = 0; kk < 12; kk++) {
            if (kk + 2 < 12) {
                int kb = (kk + 2) * 4 + q;
                awd[(kk + 2) % 3] = PBd[(size_t)kb * 128];
#pragma unroll
                for (int rt = 0; rt < 4; rt++)
                    bb[(kk + 2) % 3][rt] = *(const f16x8*)&s_x[rt * 16 + ln][(kk + 2) * 32 + q * 8];
            }
#pragma unroll
            for (int rt = 0; rt < 4; rt++)
                acc[rt] = __builtin_amdgcn_mfma_f32_16x16x32_f16(awd[kk % 3], bb[kk % 3][rt], acc[rt], 0, 0, 0);
        }
        // preload stage E weights; latency hides under epilogue + barrier
#pragma unroll
        for (int g = 0; g < 4; g++) awe[0][g] = PBe[(size_t)q * 512 + g * 128];
#pragma unroll
        for (int g = 0; g < 4; g++) awe[1][g] = PBe[(size_t)(4 + q) * 512 + g * 128];
        // epilogue: conv3 then write to the dedicated s_hH buffer (no WAR barrier
        // needed: s_hH does not alias s_x)
        int fb = w * 16 + q * 4;
        f32x4 bhv = *(const f32x4*)&bh[fb];
#pragma unroll
        for (int rt = 0; rt < 4; rt++) {
            f16x4 hp;
#pragma unroll
            for (int reg = 0; reg < 4; reg++)
                hp[reg] = (_Float16)conv3(acc[rt][reg] + bhv[reg], cw, cbv);
            *(f16x4*)&s_hH[rt * 16 + ln][fb] = hp;
        }
    }
    __syncthreads();

    // ---- Stage E: z = [h_H | hhu] @ Wz + bz; softmax gate; write out
    // wave w owns 16 z-cols (x 4 gate groups at stride 128), all 64 rows
    {
        const int nb = w * 16;
        f32x4 acc[4][4];                   // [gate group][m-tile]
#pragma unroll
        for (int g = 0; g < 4; g++)
#pragma unroll
            for (int rt = 0; rt < 4; rt++) acc[g][rt] = (f32x4){0,0,0,0};
        f16x8 bb[3][4];
#pragma unroll
        for (int rt = 0; rt < 4; rt++) bb[0][rt] = *(const f16x8*)&s_hH[rt * 16 + ln][q * 8];
#pragma unroll
        for (int rt = 0; rt < 4; rt++) bb[1][rt] = *(const f16x8*)&s_hH[rt * 16 + ln][32 + q * 8];
#pragma unroll
        for (int kk = 0; kk < 16; kk++) {
            if (kk + 2 < 16) {
                int kb = (kk + 2) * 4 + q;
#pragma unroll
                for (int g = 0; g < 4; g++) awe[(kk + 2) % 3][g] = PBe[(size_t)kb * 512 + g * 128];
                if (kk + 2 < 4) {
#pragma unroll
                    for (int rt = 0; rt < 4; rt++)
                        bb[(kk + 2) % 3][rt] = *(const f16x8*)&s_hH[rt * 16 + ln][(kk + 2) * 32 + q * 8];
                } else {
                    int k0 = (kk + 2) * 32 - 128;
#pragma unroll
                    for (int rt = 0; rt < 4; rt++)
                        bb[(kk + 2) % 3][rt] = *(const f16x8*)&s_hhu[rt * 16 + ln][k0 + q * 8];
                }
            }
#pragma unroll
            for (int g = 0; g < 4; g++)
#pragma unroll
                for (int rt = 0; rt < 4; rt++)
                    acc[g][rt] = __builtin_amdgcn_mfma_f32_16x16x32_f16(awe[kk % 3][g], bb[kk % 3][rt], acc[g][rt], 0, 0, 0);
        }
        // epilogue: lane holds z-cols colb..colb+3 (x 4 gate groups) of rows rt*16+ln
        int colb = nb + q * 4;
        f32x4 bz0 = *(const f32x4*)&bz[colb];
        f32x4 bz1 = *(const f32x4*)&bz[128 + colb];
        f32x4 bz2 = *(const f32x4*)&bz[256 + colb];
        f32x4 bz3 = *(const f32x4*)&bz[384 + colb];
#pragma unroll
        for (int rt = 0; rt < 4; rt++) {
            int row = rt * 16 + ln;
            f16x4 hH4 = *(const f16x4*)&s_hH[row][colb];
            f16x4 hL4 = *(const f16x4*)&s_hhu[row][colb];
            f16x4 hR4 = *(const f16x4*)&s_hhu[row][128 + colb];
            f16x4 u4  = *(const f16x4*)&s_hhu[row][256 + colb];
            size_t gidx = (size_t)(row0 + row) * H + colb;
            if (finalOut) {
                f32x4 ov;
#pragma unroll
                for (int reg = 0; reg < 4; reg++) {
                    float z0 = acc[0][rt][reg] + bz0[reg];
                    float z1 = acc[1][rt][reg] + bz1[reg];
                    float z2 = acc[2][rt][reg] + bz2[reg];
                    float z3 = acc[3][rt][reg] + bz3[reg];
                    float m = fmaxf(fmaxf(z0, z1), fmaxf(z2, z3));
                    float e0 = __expf(z0 - m), e1 = __expf(z1 - m), e2 = __expf(z2 - m), e3 = __expf(z3 - m);
                    float inv = __builtin_amdgcn_rcpf(e0 + e1 + e2 + e3);
                    ov[reg] = (e0 * (float)hH4[reg] + e1 * (float)hL4[reg] +
                               e2 * (float)hR4[reg] + e3 * (float)u4[reg]) * inv;
                }
                *(f32x4*)&finalOut[gidx] = ov;
            } else {
                f16x4 ev;
#pragma unroll
                for (int reg = 0; reg < 4; reg++) {
                    float z0 = acc[0][rt][reg] + bz0[reg];
                    float z1 = acc[1][rt][reg] + bz1[reg];
                    float z2 = acc[2][rt][reg] + bz2[reg];
                    float z3 = acc[3][rt][reg] + bz3[reg];
                    float m = fmaxf(fmaxf(z0, z1), fmaxf(z2, z3));
                    float e0 = __expf(z0 - m), e1 = __expf(z1 - m), e2 = __expf(z2 - m), e3 = __expf(z3 - m);
                    float inv = __builtin_amdgcn_rcpf(e0 + e1 + e2 + e3);
                    ev[reg] = (_Float16)((e0 * (float)hH4[reg] + e1 * (float)hL4[reg] +
                                          e2 * (float)hR4[reg] + e3 * (float)u4[reg]) * inv);
                }
                *(f16x4*)&embOut[gidx] = ev;
            }
        }
    }
}

extern "C" void kernel_launch(void* const* d_in, const int* in_sizes, int n_in,
                              void* d_out, int out_size, void* d_ws, size_t ws_size,
                              hipStream_t stream) {
    const float* contents = (const float*)d_in[0];
    const int*   children = (const int*)d_in[1];
    const float* Wu = (const float*)d_in[2];
    const float* bu = (const float*)d_in[3];
    const float* Wh = (const float*)d_in[4];
    const float* bh = (const float*)d_in[5];
    const float* Wz = (const float*)d_in[6];
    const float* bz = (const float*)d_in[7];
    const float* Wr = (const float*)d_in[8];
    const float* br = (const float*)d_in[9];
    const float* convw = (const float*)d_in[10];
    const float* convb = (const float*)d_in[11];
    float* out = (float*)d_out;

    // Workspace: [packed weights ~1MB][bufA 64MB][bufB 64MB]
    _Float16* Pr = (_Float16*)d_ws;
    _Float16* Ph = Pr + 384 * 384;
    _Float16* Pz = Ph + 384 * 128;
    _Float16* Pu = Pz + 512 * 512;
    _Float16* bufA = (_Float16*)((char*)d_ws + (1 << 20));
    _Float16* bufB = bufA + (size_t)262144 * H;

    auto OFFS = [](int j) -> long long { return 1024LL * ((1LL << j) - 1); };

    pack_weights<<<(512 * 512 + 255) / 256, 256, 0, stream>>>(Wu, Wr, Wh, Wz, Pu, Pr, Ph, Pz);

    // Level 8 with fused leaf (level 9) computation
    {
        int n = 1024 << 8;
        level_kernel<true><<<n / RB, NT, 0, stream>>>(
            contents + OFFS(8) * FEAT, children + OFFS(8) * 2,
            contents + OFFS(9) * FEAT, nullptr, bufA, nullptr,
            Pu, bu, Pr, br, Ph, bh, Pz, bz, convw, convb);
    }

    _Float16* prev = bufA;
    _Float16* cur  = bufB;
    for (int j = 7; j >= 0; j--) {
        int n = 1024 << j;
        level_kernel<false><<<n / RB, NT, 0, stream>>>(
            contents + OFFS(j) * FEAT, children + OFFS(j) * 2,
            nullptr, prev, cur, (j == 0 ? out : nullptr),
            Pu, bu, Pr, br, Ph, bh, Pz, bz, convw, convb);
        _Float16* tmp = prev; prev = cur; cur = tmp;
    }
}